// Round 3
// baseline (446.349 us; speedup 1.0000x reference)
//
#include <hip/hip_runtime.h>
#include <hip/hip_cooperative_groups.h>
#include <math.h>

namespace cg = cooperative_groups;

#define RANK 128
#define INV_T 20.0f      // 1 / 0.05
#define EPS_ARG 1e-7f
#define NBLK 512
#define NTHR 256

// online-softmax combine: state (m, z, w); s is a plain sum
__device__ inline void comb(float& m, float& z, float& w, float& s,
                            float m2, float z2, float w2, float s2) {
    float mn = fmaxf(m, m2);
    float a = (m  == mn) ? 1.0f : __expf(m  - mn);
    float b = (m2 == mn) ? 1.0f : __expf(m2 - mn);
    z = z * a + z2 * b;
    w = w * a + w2 * b;
    m = mn;
    s += s2;
}

__global__ void k_fused(const int* __restrict__ lca,
                        const int* __restrict__ li, const int* __restrict__ ri,
                        const float* __restrict__ sims,
                        const float* __restrict__ emb,
                        const float4* __restrict__ leaves,
                        const float* __restrict__ scale,
                        float* D, float4* partials, float* out,
                        int P, int nLeaves) {
    cg::grid_group grid = cg::this_grid();

    __shared__ float4 se1[RANK / 4];
    __shared__ float  snx[2];
    __shared__ float4 sp[NTHR / 64];

    int t = threadIdx.x;

    // ---------- Phase A: every block normalizes e1 locally (512B broadcast) ----
    if (t < 32) {
        float4 v = ((const float4*)(emb + (size_t)lca[0] * RANK))[t];
        float sq = v.x * v.x + v.y * v.y + v.z * v.z + v.w * v.w;
#pragma unroll
        for (int o = 16; o; o >>= 1) sq += __shfl_down(sq, o, 32);
        sq = __shfl(sq, 0, 32);                       // broadcast sum of squares
        float bn = sqrtf(sq);
        float s = fminf(fmaxf(scale[0], 0.01f), 1.0f - 0.001f);
        float k = s / fmaxf(bn, 1e-12f);
        float4 e; e.x = v.x * k; e.y = v.y * k; e.z = v.z * k; e.w = v.w * k;
        se1[t] = e;
        float sq2 = e.x * e.x + e.y * e.y + e.z * e.z + e.w * e.w;
#pragma unroll
        for (int o = 16; o; o >>= 1) sq2 += __shfl_down(sq2, o, 32);
        if (t == 0) {
            snx[0] = sq2;                             // nx
            snx[1] = 1.0f / (1.0f - sq2);             // 1/(1-nx)
        }
    }
    __syncthreads();

    // ---------- Phase B: per-leaf hyperbolic distance ----------
    {
        int lane = t & 63, wid = t >> 6;
        int l31 = lane & 31, half = lane >> 5;
        int wavesPerBlock = NTHR >> 6;
        int gw = blockIdx.x * wavesPerBlock + wid;
        int nw = gridDim.x * wavesPerBlock;
        float nx = snx[0], invdx = snx[1];
        float4 e = se1[l31];
        for (int jj = gw; 2 * jj < nLeaves; jj += nw) {
            int j = 2 * jj + half;
            float dot = 0.0f, ny = 0.0f;
            if (j < nLeaves) {
                float4 y = leaves[(size_t)j * (RANK / 4) + l31];  // 1KB/wave coalesced
                dot = y.x * e.x + y.y * e.y + y.z * e.z + y.w * e.w;
                ny  = y.x * y.x + y.y * y.y + y.z * y.z + y.w * y.w;
            }
#pragma unroll
            for (int o = 16; o; o >>= 1) {
                dot += __shfl_down(dot, o, 32);
                ny  += __shfl_down(ny, o, 32);
            }
            if (l31 == 0 && j < nLeaves) {
                float sq  = nx + ny - 2.0f * dot;
                float arg = 1.0f + 2.0f * sq * invdx / (1.0f - ny);
                arg = fmaxf(arg, 1.0f + EPS_ARG);
                D[j] = acoshf(arg);
            }
        }
    }
    __threadfence();
    grid.sync();

    // ---------- Phase C: fused pair loop, online softmax ----------
    {
        float m = -INFINITY, z = 0.0f, w = 0.0f, s = 0.0f;
        int tid = blockIdx.x * NTHR + t;
        int nthreads = gridDim.x * NTHR;
        int P4 = P >> 2;
        const int4*   li4 = (const int4*)li;
        const int4*   ri4 = (const int4*)ri;
        const float4* s4p = (const float4*)sims;
        for (int i = tid; i < P4; i += nthreads) {
            int4 l = li4[i], r = ri4[i];
            float4 sv = s4p[i];
            float a0 = D[l.x], b0 = D[r.x];
            float a1 = D[l.y], b1 = D[r.y];
            float a2 = D[l.z], b2 = D[r.z];
            float a3 = D[l.w], b3 = D[r.w];
            float t0 = (a0 + b0) * INV_T, t1 = (a1 + b1) * INV_T;
            float t2 = (a2 + b2) * INV_T, t3 = (a3 + b3) * INV_T;
#define STEP(tp, svv)                                                  \
            if (tp <= m) { float e = __expf(tp - m); z += e; w = fmaf(svv, e, w); } \
            else { float rr = __expf(m - tp); z = fmaf(z, rr, 1.0f); w = fmaf(w, rr, svv); m = tp; } \
            s += svv;
            STEP(t0, sv.x) STEP(t1, sv.y) STEP(t2, sv.z) STEP(t3, sv.w)
        }
        int tail0 = P4 << 2;
        for (int p = tail0 + tid; p < P; p += nthreads) {
            float tp = (D[li[p]] + D[ri[p]]) * INV_T;
            float svv = sims[p];
            STEP(tp, svv)
        }
#undef STEP
#pragma unroll
        for (int o = 32; o; o >>= 1) {
            float m2 = __shfl_xor(m, o), z2 = __shfl_xor(z, o);
            float w2 = __shfl_xor(w, o), s2 = __shfl_xor(s, o);
            comb(m, z, w, s, m2, z2, w2, s2);
        }
        int lane = t & 63, wid = t >> 6;
        if (lane == 0) sp[wid] = make_float4(m, z, w, s);
        __syncthreads();
        if (t == 0) {
            for (int i = 1; i < (NTHR >> 6); i++) {
                float4 q = sp[i];
                comb(m, z, w, s, q.x, q.y, q.z, q.w);
            }
            partials[blockIdx.x] = make_float4(m, z, w, s);
        }
    }
    __threadfence();
    grid.sync();

    // ---------- Phase D: block 0 reduces partials ----------
    if (blockIdx.x == 0) {
        float m = -INFINITY, z = 0.0f, w = 0.0f, s = 0.0f;
        for (int i = t; i < NBLK; i += NTHR) {
            float4 q = partials[i];
            comb(m, z, w, s, q.x, q.y, q.z, q.w);
        }
#pragma unroll
        for (int o = 32; o; o >>= 1) {
            float m2 = __shfl_xor(m, o), z2 = __shfl_xor(z, o);
            float w2 = __shfl_xor(w, o), s2 = __shfl_xor(s, o);
            comb(m, z, w, s, m2, z2, w2, s2);
        }
        int lane = t & 63, wid = t >> 6;
        if (lane == 0) sp[wid] = make_float4(m, z, w, s);
        __syncthreads();
        if (t == 0) {
            for (int i = 1; i < (NTHR >> 6); i++) {
                float4 q = sp[i];
                comb(m, z, w, s, q.x, q.y, q.z, q.w);
            }
            out[0] = s - w / z;
        }
    }
}

extern "C" void kernel_launch(void* const* d_in, const int* in_sizes, int n_in,
                              void* d_out, int out_size, void* d_ws, size_t ws_size,
                              hipStream_t stream) {
    const int*   lca    = (const int*)d_in[0];
    const int*   li     = (const int*)d_in[1];
    const int*   ri     = (const int*)d_in[2];
    const float* sims   = (const float*)d_in[3];
    const float* emb    = (const float*)d_in[4];
    const float* leaves = (const float*)d_in[5];
    const float* scale  = (const float*)d_in[6];
    float* out = (float*)d_out;

    int P       = in_sizes[1];
    int nLeaves = in_sizes[5] / RANK;

    char* ws = (char*)d_ws;
    float*  D        = (float*)ws;
    size_t  poff     = (((size_t)nLeaves * sizeof(float) + 1023) / 1024) * 1024;
    float4* partials = (float4*)(ws + poff);

    const float4* leaves4 = (const float4*)leaves;
    void* args[] = {
        (void*)&lca, (void*)&li, (void*)&ri, (void*)&sims, (void*)&emb,
        (void*)&leaves4, (void*)&scale, (void*)&D, (void*)&partials,
        (void*)&out, (void*)&P, (void*)&nLeaves
    };
    hipLaunchCooperativeKernel(reinterpret_cast<void*>(k_fused),
                               dim3(NBLK), dim3(NTHR), args, 0, stream);
}

// Round 4
// 221.435 us; speedup vs baseline: 2.0157x; 2.0157x over previous
//
#include <hip/hip_runtime.h>
#include <math.h>

#define RANK 128
#define INV_T 20.0f      // 1 / 0.05
#define EPS_ARG 1e-7f
#define NBLK_PAIR 512
#define NTHR 256

// online-softmax combine: state (m, z, w); s is a plain sum
__device__ inline void comb(float& m, float& z, float& w, float& s,
                            float m2, float z2, float w2, float s2) {
    float mn = fmaxf(m, m2);
    float a = (m  == mn) ? 1.0f : __expf(m  - mn);
    float b = (m2 == mn) ? 1.0f : __expf(m2 - mn);
    z = z * a + z2 * b;
    w = w * a + w2 * b;
    m = mn;
    s += s2;
}

// ---------------- k_leaf: e1 prep (per-block, redundant) + per-leaf distance ----
__global__ void k_leaf(const float* __restrict__ emb, const int* __restrict__ lca,
                       const float* __restrict__ scale,
                       const float4* __restrict__ leaves,
                       float* __restrict__ D, int* __restrict__ counter, int nLeaves) {
    __shared__ float4 se1[RANK / 4];
    __shared__ float  snx[2];
    int t = threadIdx.x;

    if (blockIdx.x == 0 && t == 0) {
        // zero the k_pair completion counter (stream order guarantees visibility)
        __hip_atomic_store(counter, 0, __ATOMIC_RELAXED, __HIP_MEMORY_SCOPE_AGENT);
    }

    // ---- per-block e1 normalization (512B broadcast read, 1 wave) ----
    if (t < 32) {
        float4 v = ((const float4*)(emb + (size_t)lca[0] * RANK))[t];
        float sq = v.x * v.x + v.y * v.y + v.z * v.z + v.w * v.w;
#pragma unroll
        for (int o = 16; o; o >>= 1) sq += __shfl_down(sq, o, 32);
        sq = __shfl(sq, 0, 32);
        float bn = sqrtf(sq);
        float s = fminf(fmaxf(scale[0], 0.01f), 1.0f - 0.001f);
        float k = s / fmaxf(bn, 1e-12f);
        float4 e; e.x = v.x * k; e.y = v.y * k; e.z = v.z * k; e.w = v.w * k;
        se1[t] = e;
        float sq2 = e.x * e.x + e.y * e.y + e.z * e.z + e.w * e.w;
#pragma unroll
        for (int o = 16; o; o >>= 1) sq2 += __shfl_down(sq2, o, 32);
        if (t == 0) {
            snx[0] = sq2;                  // nx
            snx[1] = 1.0f / (1.0f - sq2);  // 1/(1-nx)
        }
    }
    __syncthreads();

    // ---- leaf distances: one wave = 2 leaves, float4/lane coalesced ----
    int lane = t & 63, wid = t >> 6;
    int l31 = lane & 31, half = lane >> 5;
    int wavesPerBlock = NTHR >> 6;
    int gw = blockIdx.x * wavesPerBlock + wid;
    int nw = gridDim.x * wavesPerBlock;
    float nx = snx[0], invdx = snx[1];
    float4 e = se1[l31];
    for (int jj = gw; 2 * jj < nLeaves; jj += nw) {
        int j = 2 * jj + half;
        float dot = 0.0f, ny = 0.0f;
        if (j < nLeaves) {
            float4 y = leaves[(size_t)j * (RANK / 4) + l31];   // 1KB/wave
            dot = y.x * e.x + y.y * e.y + y.z * e.z + y.w * e.w;
            ny  = y.x * y.x + y.y * y.y + y.z * y.z + y.w * y.w;
        }
#pragma unroll
        for (int o = 16; o; o >>= 1) {
            dot += __shfl_down(dot, o, 32);
            ny  += __shfl_down(ny, o, 32);
        }
        if (l31 == 0 && j < nLeaves) {
            float sq  = nx + ny - 2.0f * dot;                  // ||x-y||^2
            float arg = 1.0f + 2.0f * sq * invdx / (1.0f - ny);
            arg = fmaxf(arg, 1.0f + EPS_ARG);
            D[j] = acoshf(arg);
        }
    }
}

// ---------------- k_pair: fused pair online-softmax + last-block final reduce ----
__global__ void k_pair(const int* __restrict__ li, const int* __restrict__ ri,
                       const float* __restrict__ sims, const float* __restrict__ D,
                       float4* __restrict__ partials, int* __restrict__ counter,
                       float* __restrict__ out, int P) {
    __shared__ float4 sp[NTHR / 64];
    __shared__ int isLast;
    int t = threadIdx.x;

    float m = -INFINITY, z = 0.0f, w = 0.0f, s = 0.0f;
    int tid = blockIdx.x * NTHR + t;
    int nthreads = gridDim.x * NTHR;
    int P4 = P >> 2;
    const int4*   li4 = (const int4*)li;
    const int4*   ri4 = (const int4*)ri;
    const float4* s4p = (const float4*)sims;
    for (int i = tid; i < P4; i += nthreads) {
        int4 l = li4[i], r = ri4[i];
        float4 sv = s4p[i];
        float a0 = D[l.x], b0 = D[r.x];
        float a1 = D[l.y], b1 = D[r.y];
        float a2 = D[l.z], b2 = D[r.z];
        float a3 = D[l.w], b3 = D[r.w];
        float t0 = (a0 + b0) * INV_T, t1 = (a1 + b1) * INV_T;
        float t2 = (a2 + b2) * INV_T, t3 = (a3 + b3) * INV_T;
#define STEP(tp, svv)                                                  \
        if (tp <= m) { float e = __expf(tp - m); z += e; w = fmaf(svv, e, w); } \
        else { float rr = __expf(m - tp); z = fmaf(z, rr, 1.0f); w = fmaf(w, rr, svv); m = tp; } \
        s += svv;
        STEP(t0, sv.x) STEP(t1, sv.y) STEP(t2, sv.z) STEP(t3, sv.w)
    }
    int tail0 = P4 << 2;
    for (int p = tail0 + tid; p < P; p += nthreads) {
        float tp = (D[li[p]] + D[ri[p]]) * INV_T;
        float svv = sims[p];
        STEP(tp, svv)
    }
#undef STEP
#pragma unroll
    for (int o = 32; o; o >>= 1) {
        float m2 = __shfl_xor(m, o), z2 = __shfl_xor(z, o);
        float w2 = __shfl_xor(w, o), s2 = __shfl_xor(s, o);
        comb(m, z, w, s, m2, z2, w2, s2);
    }
    int lane = t & 63, wid = t >> 6;
    if (lane == 0) sp[wid] = make_float4(m, z, w, s);
    __syncthreads();
    if (t == 0) {
        for (int i = 1; i < (NTHR >> 6); i++) {
            float4 q = sp[i];
            comb(m, z, w, s, q.x, q.y, q.z, q.w);
        }
        partials[blockIdx.x] = make_float4(m, z, w, s);
        __threadfence();   // make partials visible device-wide (release)
        int old = __hip_atomic_fetch_add(counter, 1, __ATOMIC_ACQ_REL,
                                         __HIP_MEMORY_SCOPE_AGENT);
        isLast = (old == (int)gridDim.x - 1);
    }
    __syncthreads();

    // ---- last-arriving block does the final combine ----
    if (isLast) {
        __threadfence();   // acquire: don't read stale partials
        float fm = -INFINITY, fz = 0.0f, fw = 0.0f, fs = 0.0f;
        for (int i = t; i < (int)gridDim.x; i += NTHR) {
            float4 q = partials[i];
            comb(fm, fz, fw, fs, q.x, q.y, q.z, q.w);
        }
#pragma unroll
        for (int o = 32; o; o >>= 1) {
            float m2 = __shfl_xor(fm, o), z2 = __shfl_xor(fz, o);
            float w2 = __shfl_xor(fw, o), s2 = __shfl_xor(fs, o);
            comb(fm, fz, fw, fs, m2, z2, w2, s2);
        }
        __syncthreads();   // sp reuse
        if (lane == 0) sp[wid] = make_float4(fm, fz, fw, fs);
        __syncthreads();
        if (t == 0) {
            for (int i = 1; i < (NTHR >> 6); i++) {
                float4 q = sp[i];
                comb(fm, fz, fw, fs, q.x, q.y, q.z, q.w);
            }
            out[0] = fs - fw / fz;
        }
    }
}

extern "C" void kernel_launch(void* const* d_in, const int* in_sizes, int n_in,
                              void* d_out, int out_size, void* d_ws, size_t ws_size,
                              hipStream_t stream) {
    const int*   lca    = (const int*)d_in[0];
    const int*   li     = (const int*)d_in[1];
    const int*   ri     = (const int*)d_in[2];
    const float* sims   = (const float*)d_in[3];
    const float* emb    = (const float*)d_in[4];
    const float* leaves = (const float*)d_in[5];
    const float* scale  = (const float*)d_in[6];
    float* out = (float*)d_out;

    int P       = in_sizes[1];
    int nLeaves = in_sizes[5] / RANK;

    char* ws = (char*)d_ws;
    // layout: D[nLeaves] | partials[NBLK_PAIR] (16B-aligned) | counter
    float*  D        = (float*)ws;
    size_t  poff     = (((size_t)nLeaves * sizeof(float) + 1023) / 1024) * 1024;
    float4* partials = (float4*)(ws + poff);
    int*    counter  = (int*)(ws + poff + (size_t)NBLK_PAIR * sizeof(float4));

    k_leaf<<<2048, NTHR, 0, stream>>>(emb, lca, scale, (const float4*)leaves,
                                      D, counter, nLeaves);
    k_pair<<<NBLK_PAIR, NTHR, 0, stream>>>(li, ri, sims, D, partials, counter, out, P);
}

// Round 5
// 195.011 us; speedup vs baseline: 2.2888x; 1.1355x over previous
//
#include <hip/hip_runtime.h>
#include <math.h>

#define RANK 128
#define INV_T 20.0f      // 1 / 0.05
#define EPS_ARG 1e-7f
#define NBLK_PAIR 512
#define NTHR 256

// online-softmax combine: state (m, z, w); s is a plain sum
__device__ inline void comb(float& m, float& z, float& w, float& s,
                            float m2, float z2, float w2, float s2) {
    float mn = fmaxf(m, m2);
    float a = (m  == mn) ? 1.0f : __expf(m  - mn);
    float b = (m2 == mn) ? 1.0f : __expf(m2 - mn);
    z = z * a + z2 * b;
    w = w * a + w2 * b;
    m = mn;
    s += s2;
}

// ---------------- k_leaf: e1 prep (per-block, redundant) + per-leaf distance ----
__global__ void k_leaf(const float* __restrict__ emb, const int* __restrict__ lca,
                       const float* __restrict__ scale,
                       const float4* __restrict__ leaves,
                       float* __restrict__ D, int nLeaves) {
    __shared__ float4 se1[RANK / 4];
    __shared__ float  snx[2];
    int t = threadIdx.x;

    // ---- per-block e1 normalization (512B broadcast read, 1 half-wave) ----
    if (t < 32) {
        float4 v = ((const float4*)(emb + (size_t)lca[0] * RANK))[t];
        float sq = v.x * v.x + v.y * v.y + v.z * v.z + v.w * v.w;
#pragma unroll
        for (int o = 16; o; o >>= 1) sq += __shfl_down(sq, o, 32);
        sq = __shfl(sq, 0, 32);
        float bn = sqrtf(sq);
        float s = fminf(fmaxf(scale[0], 0.01f), 1.0f - 0.001f);
        float k = s / fmaxf(bn, 1e-12f);
        float4 e; e.x = v.x * k; e.y = v.y * k; e.z = v.z * k; e.w = v.w * k;
        se1[t] = e;
        float sq2 = e.x * e.x + e.y * e.y + e.z * e.z + e.w * e.w;
#pragma unroll
        for (int o = 16; o; o >>= 1) sq2 += __shfl_down(sq2, o, 32);
        if (t == 0) {
            snx[0] = sq2;                  // nx
            snx[1] = 1.0f / (1.0f - sq2);  // 1/(1-nx)
        }
    }
    __syncthreads();

    // ---- leaf distances: one wave = 2 leaves, float4/lane coalesced ----
    int lane = t & 63, wid = t >> 6;
    int l31 = lane & 31, half = lane >> 5;
    int wavesPerBlock = NTHR >> 6;
    int gw = blockIdx.x * wavesPerBlock + wid;
    int nw = gridDim.x * wavesPerBlock;
    float nx = snx[0], invdx = snx[1];
    float4 e = se1[l31];
    for (int jj = gw; 2 * jj < nLeaves; jj += nw) {
        int j = 2 * jj + half;
        float dot = 0.0f, ny = 0.0f;
        if (j < nLeaves) {
            float4 y = leaves[(size_t)j * (RANK / 4) + l31];   // 1KB/wave
            dot = y.x * e.x + y.y * e.y + y.z * e.z + y.w * e.w;
            ny  = y.x * y.x + y.y * y.y + y.z * y.z + y.w * y.w;
        }
#pragma unroll
        for (int o = 16; o; o >>= 1) {
            dot += __shfl_down(dot, o, 32);
            ny  += __shfl_down(ny, o, 32);
        }
        if (l31 == 0 && j < nLeaves) {
            float sq  = nx + ny - 2.0f * dot;                  // ||x-y||^2
            float arg = 1.0f + 2.0f * sq * invdx / (1.0f - ny);
            arg = fmaxf(arg, 1.0f + EPS_ARG);
            D[j] = acoshf(arg);
        }
    }
}

// ---------------- k_pair: fused pair online-softmax partials (no fences) ----
__global__ void k_pair(const int* __restrict__ li, const int* __restrict__ ri,
                       const float* __restrict__ sims, const float* __restrict__ D,
                       float4* __restrict__ partials, int P) {
    float m = -INFINITY, z = 0.0f, w = 0.0f, s = 0.0f;
    int tid = blockIdx.x * NTHR + threadIdx.x;
    int nthreads = gridDim.x * NTHR;
    int P4 = P >> 2;
    const int4*   li4 = (const int4*)li;
    const int4*   ri4 = (const int4*)ri;
    const float4* s4p = (const float4*)sims;
    for (int i = tid; i < P4; i += nthreads) {
        int4 l = li4[i], r = ri4[i];
        float4 sv = s4p[i];
        float a0 = D[l.x], b0 = D[r.x];
        float a1 = D[l.y], b1 = D[r.y];
        float a2 = D[l.z], b2 = D[r.z];
        float a3 = D[l.w], b3 = D[r.w];
        float t0 = (a0 + b0) * INV_T, t1 = (a1 + b1) * INV_T;
        float t2 = (a2 + b2) * INV_T, t3 = (a3 + b3) * INV_T;
#define STEP(tp, svv)                                                  \
        if (tp <= m) { float e = __expf(tp - m); z += e; w = fmaf(svv, e, w); } \
        else { float rr = __expf(m - tp); z = fmaf(z, rr, 1.0f); w = fmaf(w, rr, svv); m = tp; } \
        s += svv;
        STEP(t0, sv.x) STEP(t1, sv.y) STEP(t2, sv.z) STEP(t3, sv.w)
    }
    int tail0 = P4 << 2;
    for (int p = tail0 + tid; p < P; p += nthreads) {
        float tp = (D[li[p]] + D[ri[p]]) * INV_T;
        float svv = sims[p];
        STEP(tp, svv)
    }
#undef STEP
#pragma unroll
    for (int o = 32; o; o >>= 1) {
        float m2 = __shfl_xor(m, o), z2 = __shfl_xor(z, o);
        float w2 = __shfl_xor(w, o), s2 = __shfl_xor(s, o);
        comb(m, z, w, s, m2, z2, w2, s2);
    }
    __shared__ float4 sp[NTHR / 64];
    int lane = threadIdx.x & 63, wid = threadIdx.x >> 6;
    if (lane == 0) sp[wid] = make_float4(m, z, w, s);
    __syncthreads();
    if (threadIdx.x == 0) {
        for (int i = 1; i < (NTHR >> 6); i++) {
            float4 q = sp[i];
            comb(m, z, w, s, q.x, q.y, q.z, q.w);
        }
        partials[blockIdx.x] = make_float4(m, z, w, s);
    }
}

// ---------------- k_fin: reduce per-block partials ----------------
__global__ void k_fin(const float4* __restrict__ partials, float* __restrict__ out, int nb) {
    int t = threadIdx.x;               // 256 threads
    float m = -INFINITY, z = 0.0f, w = 0.0f, s = 0.0f;
    for (int i = t; i < nb; i += blockDim.x) {
        float4 q = partials[i];
        comb(m, z, w, s, q.x, q.y, q.z, q.w);
    }
#pragma unroll
    for (int o = 32; o; o >>= 1) {
        float m2 = __shfl_xor(m, o), z2 = __shfl_xor(z, o);
        float w2 = __shfl_xor(w, o), s2 = __shfl_xor(s, o);
        comb(m, z, w, s, m2, z2, w2, s2);
    }
    __shared__ float4 sp[4];
    int lane = t & 63, wid = t >> 6;
    if (lane == 0) sp[wid] = make_float4(m, z, w, s);
    __syncthreads();
    if (t == 0) {
        for (int i = 1; i < (int)(blockDim.x >> 6); i++) {
            float4 q = sp[i];
            comb(m, z, w, s, q.x, q.y, q.z, q.w);
        }
        out[0] = s - w / z;
    }
}

extern "C" void kernel_launch(void* const* d_in, const int* in_sizes, int n_in,
                              void* d_out, int out_size, void* d_ws, size_t ws_size,
                              hipStream_t stream) {
    const int*   lca    = (const int*)d_in[0];
    const int*   li     = (const int*)d_in[1];
    const int*   ri     = (const int*)d_in[2];
    const float* sims   = (const float*)d_in[3];
    const float* emb    = (const float*)d_in[4];
    const float* leaves = (const float*)d_in[5];
    const float* scale  = (const float*)d_in[6];
    float* out = (float*)d_out;

    int P       = in_sizes[1];
    int nLeaves = in_sizes[5] / RANK;

    char* ws = (char*)d_ws;
    // layout: D[nLeaves] | partials[NBLK_PAIR] (16B-aligned)
    float*  D        = (float*)ws;
    size_t  poff     = (((size_t)nLeaves * sizeof(float) + 1023) / 1024) * 1024;
    float4* partials = (float4*)(ws + poff);

    k_leaf<<<2048, NTHR, 0, stream>>>(emb, lca, scale, (const float4*)leaves, D, nLeaves);
    k_pair<<<NBLK_PAIR, NTHR, 0, stream>>>(li, ri, sims, D, partials, P);
    k_fin <<<1, NTHR, 0, stream>>>(partials, out, NBLK_PAIR);
}